// Round 6
// baseline (177.696 us; speedup 1.0000x reference)
//
#include <hip/hip_runtime.h>
#include <hip/hip_fp16.h>
#include <stdint.h>

#define NPTS (96*96*96)          // 884736
#define NP5  (NPTS*5)            // 4423680 entries (point,vertex)

// Dense lattice grid (interval arithmetic from fixed domain: z,y,x in [0,95],
// image in [0,1); incl. rank-adjust, r-offset, blur padding, +/-2 margin):
//   q0 in [-3,25], q1 in [-14,14], q2 in [-16,8], q3 in [-17,3]
#define GD1 33
#define GD2 29
#define GD3 25
#define GO0 5
#define GO1 16
#define GO2 18
#define GO3 19
#define GS3 5
#define GS2 (GD3*GS3)      // 125
#define GS1 (GD2*GS2)      // 3625
#define GS0 (GD1*GS1)      // 119625
#define GCELLS (31*GS0)    // 3708375
#define GCELLS1 (GCELLS+1) // + trash cell for (never-expected) OOB
#define GSSUM (GS0+GS1+GS2+GS3)  // 123380

#define LHSR 512           // per-r sub-table slots (<=256 entries/r -> load <=0.5)

struct LatPt { int cell[5]; float w[5]; };
struct V5 { float s0, s1, s2, s3, w; };

// Per-cell value record: 12B = { q01:half2, q23:half2, w4:float }.
// Numerators fp16 (rounded per pass), denominator fp32 (exact). int3 access.

// Shared per-point lattice math macro producing rank[5], rem0i[4], b[]
#define LATTICE_MATH(n)                                                        \
  int x = n % 96, y = (n / 96) % 96, z = n / (96 * 96);                        \
  float cf[4];                                                                 \
  cf[0] = ((float)z / 5.0f) * 2.8867513459481287f;                             \
  cf[1] = ((float)y / 5.0f) * 1.6666666666666667f;                             \
  cf[2] = ((float)x / 5.0f) * 1.1785113019775793f;                             \
  cf[3] = (imgv / 0.25f) * 0.9128709291752769f;                                \
  float elev[5];                                                               \
  float sm = 0.f;                                                              \
  _Pragma("unroll")                                                            \
  for (int i = 4; i >= 1; --i){ float c = cf[i-1]; elev[i] = sm - (float)i * c; sm += c; } \
  elev[0] = sm;                                                                \
  float rem0[5]; float sumrd_f = 0.f;                                          \
  _Pragma("unroll")                                                            \
  for (int i = 0; i < 5; i++){ float rd = rintf(elev[i] / 5.0f); rem0[i] = rd * 5.0f; sumrd_f += rd; } \
  int sum_rd = (int)sumrd_f;                                                   \
  float diff[5];                                                               \
  _Pragma("unroll")                                                            \
  for (int i = 0; i < 5; i++) diff[i] = elev[i] - rem0[i];                     \
  int rank[5];                                                                 \
  _Pragma("unroll")                                                            \
  for (int i = 0; i < 5; i++){                                                 \
    int r = 0;                                                                 \
    _Pragma("unroll")                                                          \
    for (int j = 0; j < 5; j++){                                               \
      r += (diff[j] > diff[i] || (diff[j] == diff[i] && j < i)) ? 1 : 0;       \
    }                                                                          \
    rank[i] = r + sum_rd;                                                      \
  }                                                                            \
  _Pragma("unroll")                                                            \
  for (int i = 0; i < 5; i++){                                                 \
    if (rank[i] < 0)      { rank[i] += 5; rem0[i] += 5.0f; }                   \
    else if (rank[i] > 4) { rank[i] -= 5; rem0[i] -= 5.0f; }                   \
  }                                                                            \
  float b[6] = {0.f,0.f,0.f,0.f,0.f,0.f};                                      \
  _Pragma("unroll")                                                            \
  for (int i = 0; i < 5; i++){                                                 \
    float v = (elev[i] - rem0[i]) / 5.0f;                                      \
    b[4 - rank[i]] += v;                                                       \
    b[5 - rank[i]] -= v;                                                       \
  }                                                                            \
  b[0] += 1.0f + b[5];                                                         \
  int rem0i[4];                                                                \
  _Pragma("unroll")                                                            \
  for (int i = 0; i < 4; i++) rem0i[i] = (int)rem0[i];

// Dense-path per-point result (shared by build & slice — bit-identical math).
__device__ __forceinline__ LatPt lat_compute(int n, float imgv)
{
  LATTICE_MATH(n)
  LatPt p;
  #pragma unroll
  for (int r = 0; r < 5; r++){
    int q0 = (rem0i[0] / 5) - (rank[0] < 5 - r ? 0 : 1) + GO0;
    int q1 = (rem0i[1] / 5) - (rank[1] < 5 - r ? 0 : 1) + GO1;
    int q2 = (rem0i[2] / 5) - (rank[2] < 5 - r ? 0 : 1) + GO2;
    int q3 = (rem0i[3] / 5) - (rank[3] < 5 - r ? 0 : 1) + GO3;
    int cell = (((q0 * GD1 + q1) * GD2 + q2) * GD3 + q3) * 5 + r;
    if ((unsigned)cell >= (unsigned)GCELLS) cell = GCELLS;
    p.cell[r] = cell;
    p.w[r] = b[r];
  }
  return p;
}

// Phase 1: hybrid chain-build + LDS-walk aggregation (packed per-r tables).
// TWO-PASS INSERT to break the per-thread latency chain:
//   pass 1: all 5 first-probe ds_reads issued together (one round-trip
//           resolves the fast path of all 5 r's; load factor <=0.5);
//           claims CAS inside the rare resolve loop.
//   pass 2: chain-pushes (atomicExch) for dup entries are straight-line
//           independent ops -> all 5 overlap in one latency window.
__global__ void k_build_hyb(const float* __restrict__ image,
                            const float* __restrict__ input_,
                            int* __restrict__ head,
                            int4* __restrict__ nodes)
{
  __shared__ int   ls_cells[5 * LHSR];   // pos<<9 | chain-head, -1 = empty
  __shared__ short ls_next[5 * 256];     // per-entry next (511 = end)
  __shared__ float ls_w[5 * 256];
  __shared__ float ls_q[256 * 4];        // stride 4, 16B aligned -> ds_read_b128
  __shared__ short ls_slot[1280];        // dense list of occupied slots
  __shared__ int   ls_cnt;

  int tid = threadIdx.x;
  #pragma unroll
  for (int i = 0; i < (5 * LHSR) / 256; i++)
    ls_cells[tid + 256 * i] = -1;
  if (tid == 0) ls_cnt = 0;
  __syncthreads();

  int n = blockIdx.x * 256 + tid;
  float q0 = input_[n], q1 = input_[NPTS + n], q2 = input_[2 * NPTS + n], q3 = input_[3 * NPTS + n];
  *reinterpret_cast<float4*>(&ls_q[tid * 4]) = make_float4(q0, q1, q2, q3);
  LatPt P = lat_compute(n, image[n]);

  // ---- pass 1: setup + hoisted first probes ----
  int hh[5], me[5], basev[5], stat[5], curv[5];   // stat: 0=resolve,1=dup,2=claimed,3=skip
  #pragma unroll
  for (int r = 0; r < 5; r++){
    int cell = P.cell[r];
    if (cell < GCELLS){
      int pos = cell / 5;                 // exact: cell = pos*5 + r
      hh[r]    = (int)(((unsigned)pos * 2654435761u) >> 23);   // 9 bits
      basev[r] = r * LHSR;
      me[r]    = (pos << 9) | tid;
      stat[r]  = 0;
    } else {
      stat[r] = 3;
    }
  }
  #pragma unroll
  for (int r = 0; r < 5; r++)
    if (stat[r] == 0) curv[r] = ls_cells[basev[r] + hh[r]];   // 5 reads, 1 round-trip

  // ---- resolve each r (fast path: curv already decides) ----
  #pragma unroll
  for (int r = 0; r < 5; r++){
    if (stat[r] == 3) continue;
    int pos = me[r] >> 9;
    int h = hh[r];
    int cur = curv[r];
    while (true){
      if (cur == -1){
        int prev = atomicCAS(&ls_cells[basev[r] + h], -1, me[r]);
        if (prev == -1){                  // winner: tail entry + register slot
          ls_next[r * 256 + tid] = 511;
          int li = atomicAdd(&ls_cnt, 1);
          ls_slot[li] = (short)(basev[r] + h);
          stat[r] = 2; hh[r] = h;
          break;
        }
        cur = prev;                       // lost race: re-examine this slot
        continue;
      }
      if ((cur >> 9) == pos){             // same cell: push in pass 2
        stat[r] = 1; hh[r] = h;
        break;
      }
      h = (h + 1) & (LHSR - 1);
      cur = ls_cells[basev[r] + h];
    }
  }

  // ---- pass 2: independent chain pushes + weight stores ----
  #pragma unroll
  for (int r = 0; r < 5; r++){
    if (stat[r] == 1){
      int old = atomicExch(&ls_cells[basev[r] + hh[r]], me[r]);
      ls_next[r * 256 + tid] = (short)(old & 511);
    }
    if (stat[r] != 3) ls_w[r * 256 + tid] = P.w[r];
  }
  __syncthreads();

  // ---- single-chain walk (R4 structure; dual-chain reverted) ----
  int cnt = ls_cnt;
  int blockBase = blockIdx.x * 1280;
  for (int i = tid; i < cnt; i += 256){
    int slot = ls_slot[i];
    int word = ls_cells[slot];
    int r = slot >> 9;                   // sub-table id
    int pos = word >> 9;
    int cell = pos * 5 + r;
    float s0 = 0.f, s1 = 0.f, s2 = 0.f, s3 = 0.f, s4 = 0.f;
    int e = word & 511;
    while (e < 256){
      int en = ls_next[r * 256 + e];     // next-hop pointer issues first
      float w = ls_w[r * 256 + e];
      float4 q = *reinterpret_cast<const float4*>(&ls_q[e * 4]);  // b128
      s0 += w * q.x; s1 += w * q.y; s2 += w * q.z; s3 += w * q.w; s4 += w;
      e = en;
    }
    int node = blockBase + i;            // dense list position = node index
    int old = atomicExch(&head[cell], node);
    __half2 h01 = __floats2half2_rn(s0, s1);
    __half2 h23 = __floats2half2_rn(s2, s3);
    int4 raw;
    raw.x = old;
    raw.y = *reinterpret_cast<int*>(&h01);
    raw.z = *reinterpret_cast<int*>(&h23);
    raw.w = __float_as_int(s4);
    nodes[node] = raw;                   // single 16B store
  }
}

// Phase 2: gather — walk pre-summed node chains (one 16B load per hop);
// write the 12B cell record; emit occupancy bitmap via wave ballot.
__global__ void k_gather_agg(const int* __restrict__ head,
                             const int4* __restrict__ nodes,
                             int3* __restrict__ vals,
                             unsigned int* __restrict__ bitmap)
{
  int c = blockIdx.x * blockDim.x + threadIdx.x;
  int e = -1;
  if (c < GCELLS1) e = head[c];
  bool occ = (e >= 0);
  unsigned long long mask = __ballot(occ);
  int lane = threadIdx.x & 63;
  if (lane == 0)       bitmap[c >> 5] = (unsigned int)(mask & 0xffffffffu);
  else if (lane == 32) bitmap[c >> 5] = (unsigned int)(mask >> 32);
  if (c >= GCELLS1) return;

  float s0 = 0.f, s1 = 0.f, s2 = 0.f, s3 = 0.f, s4 = 0.f;
  while (e >= 0){
    int4 raw = nodes[e];                 // one 16B load: next+q01+q23+w4
    __half2 h01 = *reinterpret_cast<__half2*>(&raw.y);
    __half2 h23 = *reinterpret_cast<__half2*>(&raw.z);
    float2 f01 = __half22float2(h01);
    float2 f23 = __half22float2(h23);
    s0 += f01.x; s1 += f01.y; s2 += f23.x; s3 += f23.y;
    s4 += __int_as_float(raw.w);
    e = raw.x;
  }
  __half2 o01 = __floats2half2_rn(s0, s1);
  __half2 o23 = __floats2half2_rn(s2, s3);
  int3 rec;
  rec.x = *reinterpret_cast<int*>(&o01);
  rec.y = *reinterpret_cast<int*>(&o23);
  rec.z = __float_as_int(s4);
  vals[c] = rec;
}

// Decode + 3-point stencil of direction (dPa,dPb,dMa,dMb) at cell d.
// Returns 0-vector if d unoccupied (vin zero-invariant covers neighbors).
__device__ __forceinline__ V5 ublur(const unsigned int* __restrict__ bitmap,
                                    const int3* __restrict__ vin,
                                    int d, int dPa, int dPb, int dMa, int dMb)
{
  V5 u = {0.f, 0.f, 0.f, 0.f, 0.f};
  unsigned int wd = bitmap[d >> 5];
  if (!((wd >> (d & 31)) & 1u)) return u;
  int rd = d % 5;
  int p1 = d + (rd == 4 ? dPb : dPa);
  int p2 = d + (rd == 0 ? dMb : dMa);
  int3 a  = vin[d];
  int3 b1 = vin[p1];
  int3 b2 = vin[p2];
  float2 a01 = __half22float2(*reinterpret_cast<__half2*>(&a.x));
  float2 a23 = __half22float2(*reinterpret_cast<__half2*>(&a.y));
  float2 m01 = __half22float2(*reinterpret_cast<__half2*>(&b1.x));
  float2 m23 = __half22float2(*reinterpret_cast<__half2*>(&b1.y));
  float2 n01 = __half22float2(*reinterpret_cast<__half2*>(&b2.x));
  float2 n23 = __half22float2(*reinterpret_cast<__half2*>(&b2.y));
  u.s0 = 0.5f * a01.x + 0.25f * (m01.x + n01.x);
  u.s1 = 0.5f * a01.y + 0.25f * (m01.y + n01.y);
  u.s2 = 0.5f * a23.x + 0.25f * (m23.x + n23.x);
  u.s3 = 0.5f * a23.y + 0.25f * (m23.y + n23.y);
  u.w  = 0.5f * __int_as_float(a.z) + 0.25f * (__int_as_float(b1.z) + __int_as_float(b2.z));
  return u;
}

// Two-level stencil: value of blurB(blurA(vin)) at cell d (gated on occupancy).
__device__ __forceinline__ V5 ublur2(const unsigned int* __restrict__ bitmap,
                                     const int3* __restrict__ vin, int d,
                                     int dPaA, int dPbA, int dMaA, int dMbA,
                                     int dPaB, int dPbB, int dMaB, int dMbB)
{
  V5 o = {0.f, 0.f, 0.f, 0.f, 0.f};
  unsigned int wd = bitmap[d >> 5];
  if (!((wd >> (d & 31)) & 1u)) return o;
  int r = d % 5;
  int q1 = d + (r == 4 ? dPbB : dPaB);
  int q2 = d + (r == 0 ? dMbB : dMaB);
  V5 uc = ublur(bitmap, vin, d,  dPaA, dPbA, dMaA, dMbA);
  V5 u1 = ublur(bitmap, vin, q1, dPaA, dPbA, dMaA, dMbA);
  V5 u2 = ublur(bitmap, vin, q2, dPaA, dPbA, dMaA, dMbA);
  o.s0 = 0.5f * uc.s0 + 0.25f * (u1.s0 + u2.s0);
  o.s1 = 0.5f * uc.s1 + 0.25f * (u1.s1 + u2.s1);
  o.s2 = 0.5f * uc.s2 + 0.25f * (u1.s2 + u2.s2);
  o.s3 = 0.5f * uc.s3 + 0.25f * (u1.s3 + u2.s3);
  o.w  = 0.5f * uc.w  + 0.25f * (u1.w  + u2.w);
  return o;
}

// Phase 3a: FUSED pair of blur directions: vout = blurB(blurA(vin)).
__global__ void k_blur2_d(const unsigned int* __restrict__ bitmap,
                          const int3* __restrict__ vin,
                          int3* __restrict__ vout,
                          int dPaA, int dPbA, int dMaA, int dMbA,
                          int dPaB, int dPbB, int dMaB, int dMbB, int zfill)
{
  int c = blockIdx.x * blockDim.x + threadIdx.x;
  if (c >= GCELLS) return;
  unsigned int w = bitmap[c >> 5];
  if (!((w >> (c & 31)) & 1u)){
    if (zfill){
      int3 zero; zero.x = 0; zero.y = 0; zero.z = 0;
      vout[c] = zero;
    }
    return;
  }
  V5 o = ublur2(bitmap, vin, c, dPaA, dPbA, dMaA, dMbA, dPaB, dPbB, dMaB, dMbB);
  __half2 o01 = __floats2half2_rn(o.s0, o.s1);
  __half2 o23 = __floats2half2_rn(o.s2, o.s3);
  int3 rec;
  rec.x = *reinterpret_cast<int*>(&o01);
  rec.y = *reinterpret_cast<int*>(&o23);
  rec.z = __float_as_int(o.w);
  vout[c] = rec;
}

// Phase 3b: FUSED TRIPLE of blur directions: vout = blurC(blurB(blurA(vin))).
__global__ void k_blur3_d(const unsigned int* __restrict__ bitmap,
                          const int3* __restrict__ vin,
                          int3* __restrict__ vout,
                          int dPaA, int dPbA, int dMaA, int dMbA,
                          int dPaB, int dPbB, int dMaB, int dMbB,
                          int dPaC, int dPbC, int dMaC, int dMbC, int zfill)
{
  int c = blockIdx.x * blockDim.x + threadIdx.x;
  if (c >= GCELLS) return;
  unsigned int w = bitmap[c >> 5];
  if (!((w >> (c & 31)) & 1u)){
    if (zfill){
      int3 zero; zero.x = 0; zero.y = 0; zero.z = 0;
      vout[c] = zero;
    }
    return;
  }
  int r = c % 5;
  int p1 = c + (r == 4 ? dPbC : dPaC);
  int p2 = c + (r == 0 ? dMbC : dMaC);

  V5 uc = ublur2(bitmap, vin, c,  dPaA, dPbA, dMaA, dMbA, dPaB, dPbB, dMaB, dMbB);
  V5 u1 = ublur2(bitmap, vin, p1, dPaA, dPbA, dMaA, dMbA, dPaB, dPbB, dMaB, dMbB);
  V5 u2 = ublur2(bitmap, vin, p2, dPaA, dPbA, dMaA, dMbA, dPaB, dPbB, dMaB, dMbB);

  float o0 = 0.5f * uc.s0 + 0.25f * (u1.s0 + u2.s0);
  float o1 = 0.5f * uc.s1 + 0.25f * (u1.s1 + u2.s1);
  float o2 = 0.5f * uc.s2 + 0.25f * (u1.s2 + u2.s2);
  float o3 = 0.5f * uc.s3 + 0.25f * (u1.s3 + u2.s3);
  float ow = 0.5f * uc.w  + 0.25f * (u1.w  + u2.w);

  __half2 o01 = __floats2half2_rn(o0, o1);
  __half2 o23 = __floats2half2_rn(o2, o3);
  int3 rec;
  rec.x = *reinterpret_cast<int*>(&o01);
  rec.y = *reinterpret_cast<int*>(&o23);
  rec.z = __float_as_int(ow);
  vout[c] = rec;
}

// Phase 4: slice + normalize — recomputes cells & weights via lat_compute.
__global__ void k_slice_d(const float* __restrict__ image,
                          const int3* __restrict__ vals,
                          float* __restrict__ out)
{
  int n = blockIdx.x * blockDim.x + threadIdx.x;
  if (n >= NPTS) return;
  LatPt P = lat_compute(n, image[n]);

  float s0 = 0.f, s1 = 0.f, s2 = 0.f, s3 = 0.f, s4 = 0.f;
  #pragma unroll
  for (int r = 0; r < 5; r++){
    float w = P.w[r];
    int3 rec = vals[P.cell[r]];
    float2 f01 = __half22float2(*reinterpret_cast<__half2*>(&rec.x));
    float2 f23 = __half22float2(*reinterpret_cast<__half2*>(&rec.y));
    s0 += w * f01.x; s1 += w * f01.y; s2 += w * f23.x; s3 += w * f23.y;
    s4 += w * __int_as_float(rec.z);
  }
  float denom = s4 + 2.2204460492503131e-16f;
  out[n]            = s0 / denom;
  out[NPTS + n]     = s1 / denom;
  out[2 * NPTS + n] = s2 / denom;
  out[3 * NPTS + n] = s3 / denom;
}

// ============================ HOST ============================

extern "C" void kernel_launch(void* const* d_in, const int* in_sizes, int n_in,
                              void* d_out, int out_size, void* d_ws, size_t ws_size,
                              hipStream_t stream)
{
  const float* input_ = (const float*)d_in[0];
  const float* image  = (const float*)d_in[1];
  float* out = (float*)d_out;
  char* ws = (char*)d_ws;

  const int NB = (NPTS + 255) / 256;
  const int CB = (GCELLS1 + 255) / 256;
  const size_t BMWORDS = (size_t)CB * 8;
  const int Sj[5] = { GS0, GS1, GS2, GS3, 0 };
  int dPa[5], dPb[5], dMa[5], dMb[5];
  for (int j = 0; j < 5; j++){
    dPa[j] = 1 - Sj[j];
    dPb[j] = GSSUM - Sj[j] - 4;
    dMa[j] = Sj[j] - 1;
    dMb[j] = Sj[j] - GSSUM + 4;
  }

  // Workspace (~131 MB aliased): bitmap | head | nodes | valsA.
  // valsB ALIASED over head+nodes: both dead after k_gather_agg; the first
  // fused blur (zfill=1) zeroes valsB's empty cells over the stale bytes.
  size_t o = 0;
  size_t off_bm   = o; o += BMWORDS * 4;              o = (o + 255) & ~(size_t)255;
  size_t off_dead = o;                                 // head+nodes region
  size_t off_head = o; o += (size_t)GCELLS1 * 4;      o = (o + 255) & ~(size_t)255;
  size_t off_node = o; o += (size_t)NP5 * 16;         o = (o + 255) & ~(size_t)255;
  size_t dead_end = o;
  size_t off_vA   = o; o += (size_t)GCELLS1 * 12;
  size_t vB_need  = (size_t)GCELLS1 * 12;
  size_t off_vB   = off_dead;
  if (dead_end - off_dead < vB_need || o > ws_size){
    // non-aliased fallback layout
    off_vB = (o + 255) & ~(size_t)255;
  }

  unsigned int* bitmap = (unsigned int*)(ws + off_bm);
  int*          head   = (int*)(ws + off_head);
  int4*         nodes  = (int4*)(ws + off_node);
  int3*         valsA  = (int3*)(ws + off_vA);
  int3*         valsB  = (int3*)(ws + off_vB);

  hipMemsetAsync(head, 0xFF, (size_t)GCELLS1 * 4, stream);

  k_build_hyb<<<NB, 256, 0, stream>>>(image, input_, head, nodes);
  k_gather_agg<<<CB, 256, 0, stream>>>(head, nodes, valsA, bitmap);

  // Fused j=0+1: A -> B (zfill: B overlays stale node bytes)
  k_blur2_d<<<CB, 256, 0, stream>>>(bitmap, valsA, valsB,
                                    dPa[0], dPb[0], dMa[0], dMb[0],
                                    dPa[1], dPb[1], dMa[1], dMb[1], 1);
  // Fused TRIPLE j=2+3+4: B -> A (A's empties already zeroed by gather)
  k_blur3_d<<<CB, 256, 0, stream>>>(bitmap, valsB, valsA,
                                    dPa[2], dPb[2], dMa[2], dMb[2],
                                    dPa[3], dPb[3], dMa[3], dMb[3],
                                    dPa[4], dPb[4], dMa[4], dMb[4], 0);

  k_slice_d<<<NB, 256, 0, stream>>>(image, valsA, out);
}

// Round 7
// 168.729 us; speedup vs baseline: 1.0531x; 1.0531x over previous
//
#include <hip/hip_runtime.h>
#include <hip/hip_fp16.h>
#include <stdint.h>

#define NPTS (96*96*96)          // 884736
#define NP5  (NPTS*5)            // 4423680 entries (point,vertex)

// Dense lattice grid (interval arithmetic from fixed domain: z,y,x in [0,95],
// image in [0,1); incl. rank-adjust, r-offset, blur padding, +/-2 margin):
//   q0 in [-3,25], q1 in [-14,14], q2 in [-16,8], q3 in [-17,3]
#define GD1 33
#define GD2 29
#define GD3 25
#define GO0 5
#define GO1 16
#define GO2 18
#define GO3 19
#define GS3 5
#define GS2 (GD3*GS3)      // 125
#define GS1 (GD2*GS2)      // 3625
#define GS0 (GD1*GS1)      // 119625
#define GCELLS (31*GS0)    // 3708375
#define GCELLS1 (GCELLS+1) // + trash cell for (never-expected) OOB
#define GSSUM (GS0+GS1+GS2+GS3)  // 123380

#define LHS 2048           // block-local LDS hash slots (1280 entries -> load <=0.625)

struct LatPt { int cell[5]; float w[5]; };
struct V5 { float s0, s1, s2, s3, w; };

// Per-cell value record: 12B = { q01:half2, q23:half2, w4:float }.
// OCCUPANCY-GATED reads everywhere (bitmap): unoccupied cells are NEVER
// read, so no pass needs to zero-fill them (saves ~74 MB of zero stores).

// Shared per-point lattice math macro producing rank[5], rem0i[4], b[]
#define LATTICE_MATH(n)                                                        \
  int x = n % 96, y = (n / 96) % 96, z = n / (96 * 96);                        \
  float cf[4];                                                                 \
  cf[0] = ((float)z / 5.0f) * 2.8867513459481287f;                             \
  cf[1] = ((float)y / 5.0f) * 1.6666666666666667f;                             \
  cf[2] = ((float)x / 5.0f) * 1.1785113019775793f;                             \
  cf[3] = (imgv / 0.25f) * 0.9128709291752769f;                                \
  float elev[5];                                                               \
  float sm = 0.f;                                                              \
  _Pragma("unroll")                                                            \
  for (int i = 4; i >= 1; --i){ float c = cf[i-1]; elev[i] = sm - (float)i * c; sm += c; } \
  elev[0] = sm;                                                                \
  float rem0[5]; float sumrd_f = 0.f;                                          \
  _Pragma("unroll")                                                            \
  for (int i = 0; i < 5; i++){ float rd = rintf(elev[i] / 5.0f); rem0[i] = rd * 5.0f; sumrd_f += rd; } \
  int sum_rd = (int)sumrd_f;                                                   \
  float diff[5];                                                               \
  _Pragma("unroll")                                                            \
  for (int i = 0; i < 5; i++) diff[i] = elev[i] - rem0[i];                     \
  int rank[5];                                                                 \
  _Pragma("unroll")                                                            \
  for (int i = 0; i < 5; i++){                                                 \
    int r = 0;                                                                 \
    _Pragma("unroll")                                                          \
    for (int j = 0; j < 5; j++){                                               \
      r += (diff[j] > diff[i] || (diff[j] == diff[i] && j < i)) ? 1 : 0;       \
    }                                                                          \
    rank[i] = r + sum_rd;                                                      \
  }                                                                            \
  _Pragma("unroll")                                                            \
  for (int i = 0; i < 5; i++){                                                 \
    if (rank[i] < 0)      { rank[i] += 5; rem0[i] += 5.0f; }                   \
    else if (rank[i] > 4) { rank[i] -= 5; rem0[i] -= 5.0f; }                   \
  }                                                                            \
  float b[6] = {0.f,0.f,0.f,0.f,0.f,0.f};                                      \
  _Pragma("unroll")                                                            \
  for (int i = 0; i < 5; i++){                                                 \
    float v = (elev[i] - rem0[i]) / 5.0f;                                      \
    b[4 - rank[i]] += v;                                                       \
    b[5 - rank[i]] -= v;                                                       \
  }                                                                            \
  b[0] += 1.0f + b[5];                                                         \
  int rem0i[4];                                                                \
  _Pragma("unroll")                                                            \
  for (int i = 0; i < 4; i++) rem0i[i] = (int)rem0[i];

// Dense-path per-point result (shared by build & slice — bit-identical math).
__device__ __forceinline__ LatPt lat_compute(int n, float imgv)
{
  LATTICE_MATH(n)
  LatPt p;
  #pragma unroll
  for (int r = 0; r < 5; r++){
    int q0 = (rem0i[0] / 5) - (rank[0] < 5 - r ? 0 : 1) + GO0;
    int q1 = (rem0i[1] / 5) - (rank[1] < 5 - r ? 0 : 1) + GO1;
    int q2 = (rem0i[2] / 5) - (rank[2] < 5 - r ? 0 : 1) + GO2;
    int q3 = (rem0i[3] / 5) - (rank[3] < 5 - r ? 0 : 1) + GO3;
    int cell = (((q0 * GD1 + q1) * GD2 + q2) * GD3 + q3) * 5 + r;
    if ((unsigned)cell >= (unsigned)GCELLS) cell = GCELLS;
    p.cell[r] = cell;
    p.w[r] = b[r];
  }
  return p;
}

// Phase 1: hybrid chain-build + LDS-walk aggregation (R0 structure verbatim —
// best-measured build variant: 49-51 us).
__global__ void k_build_hyb(const float* __restrict__ image,
                            const float* __restrict__ input_,
                            int* __restrict__ head,
                            int4* __restrict__ nodes)
{
  __shared__ int   ls_cell[LHS];
  __shared__ int   ls_head[LHS];
  __shared__ short ls_next[1280];
  __shared__ float ls_w[1280];
  __shared__ float ls_q[256 * 4];     // stride 4, 16B aligned -> ds_read_b128
  __shared__ short ls_slot[1280];     // dense list of occupied slots
  __shared__ int   ls_cnt;

  int tid = threadIdx.x;
  #pragma unroll
  for (int i = 0; i < LHS / 256; i++){
    ls_cell[tid + 256 * i] = -1;
    ls_head[tid + 256 * i] = -1;
  }
  if (tid == 0) ls_cnt = 0;
  __syncthreads();

  int n = blockIdx.x * 256 + tid;
  float q0 = input_[n], q1 = input_[NPTS + n], q2 = input_[2 * NPTS + n], q3 = input_[3 * NPTS + n];
  *reinterpret_cast<float4*>(&ls_q[tid * 4]) = make_float4(q0, q1, q2, q3);
  LatPt P = lat_compute(n, image[n]);

  #pragma unroll
  for (int r = 0; r < 5; r++){
    int cell = P.cell[r];
    unsigned int h = ((unsigned int)cell * 2654435761u) & (LHS - 1);
    while (true){
      int prev = atomicCAS(&ls_cell[h], -1, cell);
      if (prev == -1){
        int li = atomicAdd(&ls_cnt, 1);      // winner registers the slot
        ls_slot[li] = (short)h;
        break;
      }
      if (prev == cell) break;
      h = (h + 1) & (LHS - 1);
    }
    int e = tid * 5 + r;
    ls_w[e] = P.w[r];
    ls_next[e] = (short)atomicExch(&ls_head[h], e);   // local chain push
  }
  __syncthreads();

  int cnt = ls_cnt;
  int blockBase = blockIdx.x * 1280;
  for (int i = tid; i < cnt; i += 256){
    int slot = ls_slot[i];
    int cell = ls_cell[slot];
    float s0 = 0.f, s1 = 0.f, s2 = 0.f, s3 = 0.f, s4 = 0.f;
    int e = ls_head[slot];
    while (e >= 0){
      int en = ls_next[e];                 // next-hop pointer issues first
      float w = ls_w[e];
      float4 q = *reinterpret_cast<const float4*>(&ls_q[(e / 5) * 4]);  // b128
      s0 += w * q.x; s1 += w * q.y; s2 += w * q.z; s3 += w * q.w; s4 += w;
      e = en;
    }
    int node = blockBase + i;              // dense list position = node index
    int old = atomicExch(&head[cell], node);
    __half2 h01 = __floats2half2_rn(s0, s1);
    __half2 h23 = __floats2half2_rn(s2, s3);
    int4 raw;
    raw.x = old;
    raw.y = *reinterpret_cast<int*>(&h01);
    raw.z = *reinterpret_cast<int*>(&h23);
    raw.w = __float_as_int(s4);
    nodes[node] = raw;                     // single 16B store
  }
}

// Phase 2: gather — walk pre-summed node chains (one 16B load per hop);
// write the 12B cell record for OCCUPIED cells only; emit occupancy bitmap.
__global__ void k_gather_agg(const int* __restrict__ head,
                             const int4* __restrict__ nodes,
                             int3* __restrict__ vals,
                             unsigned int* __restrict__ bitmap)
{
  int c = blockIdx.x * blockDim.x + threadIdx.x;
  int e = -1;
  if (c < GCELLS1) e = head[c];
  bool occ = (e >= 0);
  unsigned long long mask = __ballot(occ);
  int lane = threadIdx.x & 63;
  if (lane == 0)       bitmap[c >> 5] = (unsigned int)(mask & 0xffffffffu);
  else if (lane == 32) bitmap[c >> 5] = (unsigned int)(mask >> 32);
  if (!occ) return;                      // unoccupied cells are never read

  float s0 = 0.f, s1 = 0.f, s2 = 0.f, s3 = 0.f, s4 = 0.f;
  while (e >= 0){
    int4 raw = nodes[e];                 // one 16B load: next+q01+q23+w4
    __half2 h01 = *reinterpret_cast<__half2*>(&raw.y);
    __half2 h23 = *reinterpret_cast<__half2*>(&raw.z);
    float2 f01 = __half22float2(h01);
    float2 f23 = __half22float2(h23);
    s0 += f01.x; s1 += f01.y; s2 += f23.x; s3 += f23.y;
    s4 += __int_as_float(raw.w);
    e = raw.x;
  }
  __half2 o01 = __floats2half2_rn(s0, s1);
  __half2 o23 = __floats2half2_rn(s2, s3);
  int3 rec;
  rec.x = *reinterpret_cast<int*>(&o01);
  rec.y = *reinterpret_cast<int*>(&o23);
  rec.z = __float_as_int(s4);
  vals[c] = rec;
}

// Decode + 3-point stencil of direction (dPa,dPb,dMa,dMb) at cell d.
// Neighbor values are BITMAP-GATED (predicated zeroing of raw words) — vin
// holds garbage at unoccupied cells and is never trusted there.
__device__ __forceinline__ V5 ublur(const unsigned int* __restrict__ bitmap,
                                    const int3* __restrict__ vin,
                                    int d, int dPa, int dPb, int dMa, int dMb)
{
  V5 u = {0.f, 0.f, 0.f, 0.f, 0.f};
  if (!((bitmap[d >> 5] >> (d & 31)) & 1u)) return u;
  int rd = d % 5;
  int p1 = d + (rd == 4 ? dPb : dPa);
  int p2 = d + (rd == 0 ? dMb : dMa);
  bool o1 = (bitmap[p1 >> 5] >> (p1 & 31)) & 1u;
  bool o2 = (bitmap[p2 >> 5] >> (p2 & 31)) & 1u;
  int3 a  = vin[d];
  int3 b1 = vin[p1];                   // in-bounds by grid margin; gated below
  int3 b2 = vin[p2];
  if (!o1){ b1.x = 0; b1.y = 0; b1.z = 0; }
  if (!o2){ b2.x = 0; b2.y = 0; b2.z = 0; }
  float2 a01 = __half22float2(*reinterpret_cast<__half2*>(&a.x));
  float2 a23 = __half22float2(*reinterpret_cast<__half2*>(&a.y));
  float2 m01 = __half22float2(*reinterpret_cast<__half2*>(&b1.x));
  float2 m23 = __half22float2(*reinterpret_cast<__half2*>(&b1.y));
  float2 n01 = __half22float2(*reinterpret_cast<__half2*>(&b2.x));
  float2 n23 = __half22float2(*reinterpret_cast<__half2*>(&b2.y));
  u.s0 = 0.5f * a01.x + 0.25f * (m01.x + n01.x);
  u.s1 = 0.5f * a01.y + 0.25f * (m01.y + n01.y);
  u.s2 = 0.5f * a23.x + 0.25f * (m23.x + n23.x);
  u.s3 = 0.5f * a23.y + 0.25f * (m23.y + n23.y);
  u.w  = 0.5f * __int_as_float(a.z) + 0.25f * (__int_as_float(b1.z) + __int_as_float(b2.z));
  return u;
}

// Two-level stencil: value of blurB(blurA(vin)) at cell d (gated on occupancy).
__device__ __forceinline__ V5 ublur2(const unsigned int* __restrict__ bitmap,
                                     const int3* __restrict__ vin, int d,
                                     int dPaA, int dPbA, int dMaA, int dMbA,
                                     int dPaB, int dPbB, int dMaB, int dMbB)
{
  V5 o = {0.f, 0.f, 0.f, 0.f, 0.f};
  if (!((bitmap[d >> 5] >> (d & 31)) & 1u)) return o;
  int r = d % 5;
  int q1 = d + (r == 4 ? dPbB : dPaB);
  int q2 = d + (r == 0 ? dMbB : dMaB);
  V5 uc = ublur(bitmap, vin, d,  dPaA, dPbA, dMaA, dMbA);
  V5 u1 = ublur(bitmap, vin, q1, dPaA, dPbA, dMaA, dMbA);
  V5 u2 = ublur(bitmap, vin, q2, dPaA, dPbA, dMaA, dMbA);
  o.s0 = 0.5f * uc.s0 + 0.25f * (u1.s0 + u2.s0);
  o.s1 = 0.5f * uc.s1 + 0.25f * (u1.s1 + u2.s1);
  o.s2 = 0.5f * uc.s2 + 0.25f * (u1.s2 + u2.s2);
  o.s3 = 0.5f * uc.s3 + 0.25f * (u1.s3 + u2.s3);
  o.w  = 0.5f * uc.w  + 0.25f * (u1.w  + u2.w);
  return o;
}

// Phase 3a: FUSED pair of blur directions: vout = blurB(blurA(vin)).
// Writes occupied cells only (reads are gated; no zero-fill needed).
__global__ void k_blur2_d(const unsigned int* __restrict__ bitmap,
                          const int3* __restrict__ vin,
                          int3* __restrict__ vout,
                          int dPaA, int dPbA, int dMaA, int dMbA,
                          int dPaB, int dPbB, int dMaB, int dMbB)
{
  int c = blockIdx.x * blockDim.x + threadIdx.x;
  if (c >= GCELLS) return;
  if (!((bitmap[c >> 5] >> (c & 31)) & 1u)) return;
  V5 o = ublur2(bitmap, vin, c, dPaA, dPbA, dMaA, dMbA, dPaB, dPbB, dMaB, dMbB);
  __half2 o01 = __floats2half2_rn(o.s0, o.s1);
  __half2 o23 = __floats2half2_rn(o.s2, o.s3);
  int3 rec;
  rec.x = *reinterpret_cast<int*>(&o01);
  rec.y = *reinterpret_cast<int*>(&o23);
  rec.z = __float_as_int(o.w);
  vout[c] = rec;
}

// Phase 3b: FUSED TRIPLE of blur directions: vout = blurC(blurB(blurA(vin))).
// Writes occupied cells only.
__global__ void k_blur3_d(const unsigned int* __restrict__ bitmap,
                          const int3* __restrict__ vin,
                          int3* __restrict__ vout,
                          int dPaA, int dPbA, int dMaA, int dMbA,
                          int dPaB, int dPbB, int dMaB, int dMbB,
                          int dPaC, int dPbC, int dMaC, int dMbC)
{
  int c = blockIdx.x * blockDim.x + threadIdx.x;
  if (c >= GCELLS) return;
  if (!((bitmap[c >> 5] >> (c & 31)) & 1u)) return;
  int r = c % 5;
  int p1 = c + (r == 4 ? dPbC : dPaC);
  int p2 = c + (r == 0 ? dMbC : dMaC);

  V5 uc = ublur2(bitmap, vin, c,  dPaA, dPbA, dMaA, dMbA, dPaB, dPbB, dMaB, dMbB);
  V5 u1 = ublur2(bitmap, vin, p1, dPaA, dPbA, dMaA, dMbA, dPaB, dPbB, dMaB, dMbB);
  V5 u2 = ublur2(bitmap, vin, p2, dPaA, dPbA, dMaA, dMbA, dPaB, dPbB, dMaB, dMbB);

  float o0 = 0.5f * uc.s0 + 0.25f * (u1.s0 + u2.s0);
  float o1 = 0.5f * uc.s1 + 0.25f * (u1.s1 + u2.s1);
  float o2 = 0.5f * uc.s2 + 0.25f * (u1.s2 + u2.s2);
  float o3 = 0.5f * uc.s3 + 0.25f * (u1.s3 + u2.s3);
  float ow = 0.5f * uc.w  + 0.25f * (u1.w  + u2.w);

  __half2 o01 = __floats2half2_rn(o0, o1);
  __half2 o23 = __floats2half2_rn(o2, o3);
  int3 rec;
  rec.x = *reinterpret_cast<int*>(&o01);
  rec.y = *reinterpret_cast<int*>(&o23);
  rec.z = __float_as_int(ow);
  vout[c] = rec;
}

// Phase 4: slice + normalize — recomputes cells & weights via lat_compute.
// Every sliced cell is occupied by construction (it received this point's
// splat), so no gating needed here.
__global__ void k_slice_d(const float* __restrict__ image,
                          const int3* __restrict__ vals,
                          float* __restrict__ out)
{
  int n = blockIdx.x * blockDim.x + threadIdx.x;
  if (n >= NPTS) return;
  LatPt P = lat_compute(n, image[n]);

  float s0 = 0.f, s1 = 0.f, s2 = 0.f, s3 = 0.f, s4 = 0.f;
  #pragma unroll
  for (int r = 0; r < 5; r++){
    float w = P.w[r];
    int3 rec = vals[P.cell[r]];
    float2 f01 = __half22float2(*reinterpret_cast<__half2*>(&rec.x));
    float2 f23 = __half22float2(*reinterpret_cast<__half2*>(&rec.y));
    s0 += w * f01.x; s1 += w * f01.y; s2 += w * f23.x; s3 += w * f23.y;
    s4 += w * __int_as_float(rec.z);
  }
  float denom = s4 + 2.2204460492503131e-16f;
  out[n]            = s0 / denom;
  out[NPTS + n]     = s1 / denom;
  out[2 * NPTS + n] = s2 / denom;
  out[3 * NPTS + n] = s3 / denom;
}

// ============================ HOST ============================

extern "C" void kernel_launch(void* const* d_in, const int* in_sizes, int n_in,
                              void* d_out, int out_size, void* d_ws, size_t ws_size,
                              hipStream_t stream)
{
  const float* input_ = (const float*)d_in[0];
  const float* image  = (const float*)d_in[1];
  float* out = (float*)d_out;
  char* ws = (char*)d_ws;

  const int NB = (NPTS + 255) / 256;
  const int CB = (GCELLS1 + 255) / 256;
  const size_t BMWORDS = (size_t)CB * 8;
  const int Sj[5] = { GS0, GS1, GS2, GS3, 0 };
  int dPa[5], dPb[5], dMa[5], dMb[5];
  for (int j = 0; j < 5; j++){
    dPa[j] = 1 - Sj[j];
    dPb[j] = GSSUM - Sj[j] - 4;
    dMa[j] = Sj[j] - 1;
    dMb[j] = Sj[j] - GSSUM + 4;
  }

  // Workspace (~131 MB aliased): bitmap | head | nodes | valsA.
  // valsB ALIASED over head+nodes (dead after k_gather_agg). Stale bytes in
  // unoccupied cells of either vals buffer are NEVER read (bitmap gating).
  size_t o = 0;
  size_t off_bm   = o; o += BMWORDS * 4;              o = (o + 255) & ~(size_t)255;
  size_t off_dead = o;                                 // head+nodes region
  size_t off_head = o; o += (size_t)GCELLS1 * 4;      o = (o + 255) & ~(size_t)255;
  size_t off_node = o; o += (size_t)NP5 * 16;         o = (o + 255) & ~(size_t)255;
  size_t dead_end = o;
  size_t off_vA   = o; o += (size_t)GCELLS1 * 12;
  size_t vB_need  = (size_t)GCELLS1 * 12;
  size_t off_vB   = off_dead;
  if (dead_end - off_dead < vB_need || o > ws_size){
    // non-aliased fallback layout
    off_vB = (o + 255) & ~(size_t)255;
  }

  unsigned int* bitmap = (unsigned int*)(ws + off_bm);
  int*          head   = (int*)(ws + off_head);
  int4*         nodes  = (int4*)(ws + off_node);
  int3*         valsA  = (int3*)(ws + off_vA);
  int3*         valsB  = (int3*)(ws + off_vB);

  hipMemsetAsync(head, 0xFF, (size_t)GCELLS1 * 4, stream);

  k_build_hyb<<<NB, 256, 0, stream>>>(image, input_, head, nodes);
  k_gather_agg<<<CB, 256, 0, stream>>>(head, nodes, valsA, bitmap);

  // Fused j=0+1: A -> B (occupied-only writes; gated reads)
  k_blur2_d<<<CB, 256, 0, stream>>>(bitmap, valsA, valsB,
                                    dPa[0], dPb[0], dMa[0], dMb[0],
                                    dPa[1], dPb[1], dMa[1], dMb[1]);
  // Fused TRIPLE j=2+3+4: B -> A
  k_blur3_d<<<CB, 256, 0, stream>>>(bitmap, valsB, valsA,
                                    dPa[2], dPb[2], dMa[2], dMb[2],
                                    dPa[3], dPb[3], dMa[3], dMb[3],
                                    dPa[4], dPb[4], dMa[4], dMb[4]);

  k_slice_d<<<NB, 256, 0, stream>>>(image, valsA, out);
}